// Round 1
// baseline (1823.221 us; speedup 1.0000x reference)
//
#include <hip/hip_runtime.h>

#define NUM_CAT 16
#define NUM_ATTR 144
#define NUM_NUM 128
#define N_ARY 32
#define NUM_SEG 100000
#define N_ROWS 1000000

// ws layout:
//   int   hdr_i[0..31]  : selcol[j] = 16 + top_num_idx[j] (full-row column)
//   float hdr_f[32..63] : conf[j]
//   int   hdr_i[64]     : topcat (argmax of cat_mask)
//   byte offset 512     : float agg[NUM_SEG*32]  (12.8 MB)
#define AGG_OFFSET 512

__global__ void setup_kernel(const float* __restrict__ cat_mask,
                             const float* __restrict__ num_mask,
                             int* __restrict__ hdr_i,
                             float* __restrict__ hdr_f) {
    if (threadIdx.x != 0 || blockIdx.x != 0) return;

    // --- cat softmax: top-1 value and argmax index ---
    float cmax = cat_mask[0]; int cidx = 0;
    for (int i = 1; i < NUM_CAT; ++i) {
        float v = cat_mask[i];
        if (v > cmax) { cmax = v; cidx = i; }   // strict > : ties -> lower idx
    }
    float csum = 0.f;
    for (int i = 0; i < NUM_CAT; ++i) csum += expf(cat_mask[i] - cmax);
    float top_cat_val = 1.0f / csum;            // exp(0)/sum
    hdr_i[64] = cidx;

    // --- numeric softmax + top-32 (descending, ties -> lower idx) ---
    float nmax = num_mask[0];
    for (int i = 1; i < NUM_NUM; ++i) nmax = fmaxf(nmax, num_mask[i]);
    float nm[NUM_NUM];
    float nsum = 0.f;
    for (int i = 0; i < NUM_NUM; ++i) { nm[i] = expf(num_mask[i] - nmax); nsum += nm[i]; }
    float inv = 1.0f / nsum;

    bool used[NUM_NUM];
    for (int i = 0; i < NUM_NUM; ++i) used[i] = false;
    for (int k = 0; k < N_ARY; ++k) {
        float best = -1.f; int bi = 0;
        for (int i = 0; i < NUM_NUM; ++i) {
            if (!used[i] && nm[i] > best) { best = nm[i]; bi = i; }
        }
        used[bi] = true;
        hdr_i[k] = NUM_CAT + bi;                       // column in full input row
        hdr_f[32 + k] = 0.5f * (best * inv + top_cat_val);  // conf[k]
    }
}

__global__ void accum_kernel(const float* __restrict__ inputs,
                             const int* __restrict__ idx,
                             const int* __restrict__ hdr_i,
                             float* __restrict__ agg) {
    const int j = threadIdx.x & 31;          // invariant: stride % 32 == 0
    const int col = hdr_i[j];
    const int topcat = hdr_i[64];
    const int total = N_ROWS * 32;
    int t = blockIdx.x * blockDim.x + threadIdx.x;
    const int stride = gridDim.x * blockDim.x;
    for (; t < total; t += stride) {
        int row = t >> 5;
        int seg = idx[row * NUM_CAT + topcat];
        float v = inputs[row * NUM_ATTR + col];
        atomicAdd(&agg[seg * 32 + j], v);
    }
}

__global__ void gather_kernel(const int* __restrict__ idx,
                              const int* __restrict__ hdr_i,
                              const float* __restrict__ hdr_f,
                              const float* __restrict__ agg,
                              float* __restrict__ out) {
    const int j = threadIdx.x & 31;
    const float cf = hdr_f[32 + j];
    const int topcat = hdr_i[64];
    const int total = N_ROWS * 32;
    int t = blockIdx.x * blockDim.x + threadIdx.x;
    const int stride = gridDim.x * blockDim.x;
    for (; t < total; t += stride) {
        int row = t >> 5;
        int seg = idx[row * NUM_CAT + topcat];
        out[t] = agg[seg * 32 + j] * cf;
    }
}

extern "C" void kernel_launch(void* const* d_in, const int* in_sizes, int n_in,
                              void* d_out, int out_size, void* d_ws, size_t ws_size,
                              hipStream_t stream) {
    const float* inputs   = (const float*)d_in[0];   // (1M, 144) f32
    const int*   idx      = (const int*)d_in[1];     // (1M, 16) int
    const float* cat_mask = (const float*)d_in[2];   // (16,)
    const float* num_mask = (const float*)d_in[3];   // (128,)
    float* out = (float*)d_out;                      // (1M, 32) f32

    int*   hdr_i = (int*)d_ws;
    float* hdr_f = (float*)d_ws;
    float* agg   = (float*)((char*)d_ws + AGG_OFFSET);

    // 1) mask math -> header
    setup_kernel<<<1, 64, 0, stream>>>(cat_mask, num_mask, hdr_i, hdr_f);

    // 2) zero agg (memset node is graph-capture safe)
    hipMemsetAsync(agg, 0, (size_t)NUM_SEG * 32 * sizeof(float), stream);

    // 3) segment-sum of the 32 selected columns
    accum_kernel<<<8192, 256, 0, stream>>>(inputs, idx, hdr_i, agg);

    // 4) gather + scale
    gather_kernel<<<8192, 256, 0, stream>>>(idx, hdr_i, hdr_f, agg, out);
}